// Round 2
// baseline (561.373 us; speedup 1.0000x reference)
//
#include <hip/hip_runtime.h>
#include <hip/hip_bf16.h>

#define M_DIM 8192
#define N_DIM 4096
#define K_DIM 4096
#define BM 128
#define BN 128
#define BK 32

typedef __bf16 bf16x8 __attribute__((ext_vector_type(8)));
typedef float  f32x4  __attribute__((ext_vector_type(4)));
typedef unsigned short u16x8 __attribute__((ext_vector_type(8)));

// async global->LDS, 16B per lane, dest = wave-uniform base + lane*16
#define ASYNC16(g, l)                                                          \
  __builtin_amdgcn_global_load_lds(                                            \
      (__attribute__((address_space(1))) void*)(g),                            \
      (__attribute__((address_space(3))) void*)(l), 16, 0, 0)

static __device__ __forceinline__ unsigned short f2bf(float f) {
  unsigned int u = __float_as_uint(f);
  u += 0x7fffu + ((u >> 16) & 1u);   // round-to-nearest-even
  return (unsigned short)(u >> 16);
}

// ---- fused prep: blocks [0,N) build W rows CSR-style; rest convert x --------
// W rows: COO from jnp.nonzero is sorted by row -> binary search the range,
// compose the dense bf16 row in LDS (zero + scatter + coalesced store).
__global__ __launch_bounds__(256) void sl_prep(
    const float4* __restrict__ x4, u16x8* __restrict__ xb,
    const float* __restrict__ vals, const int* __restrict__ rows,
    const int* __restrict__ cols, unsigned short* __restrict__ W, int nnz) {
  const int b = blockIdx.x;
  if (b < N_DIM) {
    __shared__ __align__(16) unsigned short rowbuf[K_DIM];  // 8 KB
    u16x8* rb8 = (u16x8*)rowbuf;
    u16x8 z = {};
    rb8[threadIdx.x] = z;
    rb8[256 + threadIdx.x] = z;
    __syncthreads();
    // binary search [s,e) of nnz belonging to row b (rows[] ascending)
    int l = 0, h = nnz;
    while (l < h) { int m = (l + h) >> 1; if (rows[m] < b) l = m + 1; else h = m; }
    const int s = l;
    h = nnz;
    while (l < h) { int m = (l + h) >> 1; if (rows[m] <= b) l = m + 1; else h = m; }
    const int e = l;
    for (int k = s + threadIdx.x; k < e; k += 256)
      rowbuf[cols[k]] = f2bf(vals[k]);
    __syncthreads();
    u16x8* dst = (u16x8*)(W + (size_t)b * K_DIM);
    dst[threadIdx.x] = rb8[threadIdx.x];
    dst[256 + threadIdx.x] = rb8[256 + threadIdx.x];
  } else {
    // x fp32 -> bf16, 8 elements/thread
    const int i = (b - N_DIM) * 256 + threadIdx.x;
    float4 a = x4[2 * i];
    float4 c = x4[2 * i + 1];
    u16x8 o;
    o[0] = f2bf(a.x); o[1] = f2bf(a.y); o[2] = f2bf(a.z); o[3] = f2bf(a.w);
    o[4] = f2bf(c.x); o[5] = f2bf(c.y); o[6] = f2bf(c.z); o[7] = f2bf(c.w);
    xb[i] = o;
  }
}

// ---- bf16 MFMA GEMM: C[m][n] = sum_k A[m,k]*B[n,k] + bias[n] ----------------
// block 256 = 4 waves (2x2), wave computes 64x64 = 4x4 MFMA tiles of 16x16x32.
// LDS layout XOR-swizzled: 16B chunk for (row, cb) lives at physical chunk
//   p = 4*row + (cb ^ ((row>>1)&3))
// so a fragment read's consecutive-8-lane phases hit all 8 bank groups
// exactly once (2-way aliasing only = free). Staging keeps the HW-fixed
// LDS dest (base + lane*16) and swizzles the GLOBAL source column instead.
__global__ __launch_bounds__(256) void sl_gemm_bias(
    const unsigned short* __restrict__ A,   // x bf16 [M,K]
    const unsigned short* __restrict__ B,   // W bf16 [N,K]
    const float* __restrict__ bias,
    float* __restrict__ C) {
  __shared__ __align__(16) unsigned short As[BM * BK]; // 8 KB
  __shared__ __align__(16) unsigned short Bs[BN * BK]; // 8 KB

  const int tid  = threadIdx.x;
  const int wave = tid >> 6;
  const int lane = tid & 63;
  const int m0 = blockIdx.x * BM;
  const int n0 = blockIdx.y * BN;

  // --- staging: physical chunk (round*256 + tid) holds row = 64*round + tid>>2,
  //     logical colblock = (tid&3) ^ ((tid>>3)&3)  (XOR swizzle, round-invariant)
  const int srow = tid >> 2;                          // 0..63
  const int scol = ((tid & 3) ^ ((tid >> 3) & 3)) * 8; // swizzled bf16 col in BK
  const unsigned short* gA0 = A + (size_t)(m0 + srow) * K_DIM + scol;
  const unsigned short* gA1 = gA0 + (size_t)64 * K_DIM;
  const unsigned short* gB0 = B + (size_t)(n0 + srow) * K_DIM + scol;
  const unsigned short* gB1 = gB0 + (size_t)64 * K_DIM;
  unsigned short* lA0 = As + (size_t)(wave * 64) * 8;        // wave-uniform bases
  unsigned short* lA1 = As + (size_t)(256 + wave * 64) * 8;
  unsigned short* lB0 = Bs + (size_t)(wave * 64) * 8;
  unsigned short* lB1 = Bs + (size_t)(256 + wave * 64) * 8;

  // --- fragment addressing
  const int wm   = (wave >> 1) * 64;
  const int wn   = (wave & 1) * 64;
  const int fm   = lane & 15;
  const int quad = lane >> 4;
  const int sw   = (fm >> 1) & 3;          // row-dependent part of the swizzle
  const int kc   = (quad ^ sw) * 8;        // swizzled k-chunk offset (bf16 elems)

  f32x4 acc[4][4] = {};

  for (int k0 = 0; k0 < K_DIM; k0 += BK) {
    ASYNC16(gA0, lA0);
    ASYNC16(gA1, lA1);
    ASYNC16(gB0, lB0);
    ASYNC16(gB1, lB1);
    gA0 += BK; gA1 += BK; gB0 += BK; gB1 += BK;
    __syncthreads();   // drains vmcnt -> LDS tiles complete

    bf16x8 af[4], bfr[4];
#pragma unroll
    for (int t = 0; t < 4; ++t) {
      af[t]  = *(const bf16x8*)(As + (size_t)(wm + t * 16 + fm) * BK + kc);
      bfr[t] = *(const bf16x8*)(Bs + (size_t)(wn + t * 16 + fm) * BK + kc);
    }
#pragma unroll
    for (int tm = 0; tm < 4; ++tm)
#pragma unroll
      for (int tn = 0; tn < 4; ++tn)
        acc[tm][tn] = __builtin_amdgcn_mfma_f32_16x16x32_bf16(
            af[tm], bfr[tn], acc[tm][tn], 0, 0, 0);
    __syncthreads();   // all waves done reading before next staging overwrites
  }

  // --- epilogue: D row = A-index (quad*4+reg), col = B-index (lane&15)
  float bv[4];
#pragma unroll
  for (int tn = 0; tn < 4; ++tn) bv[tn] = bias[n0 + wn + tn * 16 + fm];

#pragma unroll
  for (int tm = 0; tm < 4; ++tm) {
    const int mbase = m0 + wm + tm * 16 + quad * 4;
#pragma unroll
    for (int tn = 0; tn < 4; ++tn) {
      const int n = n0 + wn + tn * 16 + fm;
      float* p = C + (size_t)mbase * N_DIM + n;
#pragma unroll
      for (int r = 0; r < 4; ++r)
        p[(size_t)r * N_DIM] = acc[tm][tn][r] + bv[tn];
    }
  }
}

// ---- fallback (only if workspace too small): naive fp32 SpMM ----------------
__global__ void sl_naive(const float* __restrict__ x, const float* __restrict__ vals,
                         const int* __restrict__ rows, const int* __restrict__ cols,
                         const float* __restrict__ bias, float* __restrict__ out,
                         int nnz) {
  const int o = blockIdx.x;
  int l = 0, h = nnz;
  while (l < h) { int m = (l + h) >> 1; if (rows[m] < o) l = m + 1; else h = m; }
  const int s = l;
  h = nnz;
  while (l < h) { int m = (l + h) >> 1; if (rows[m] <= o) l = m + 1; else h = m; }
  const int e = l;
  const float bv = bias[o];
  for (int b = threadIdx.x; b < M_DIM; b += blockDim.x) {
    float acc = bv;
    const float* xb = x + (size_t)b * K_DIM;
    for (int k = s; k < e; ++k) acc += vals[k] * xb[cols[k]];
    out[(size_t)b * N_DIM + o] = acc;
  }
}

extern "C" void kernel_launch(void* const* d_in, const int* in_sizes, int n_in,
                              void* d_out, int out_size, void* d_ws, size_t ws_size,
                              hipStream_t stream) {
  const float* x    = (const float*)d_in[0];
  const float* vals = (const float*)d_in[1];
  const int*   rows = (const int*)d_in[2];
  const int*   cols = (const int*)d_in[3];
  const float* bias = (const float*)d_in[4];
  float* out = (float*)d_out;
  const int nnz = in_sizes[1];

  const size_t xb_bytes = (size_t)M_DIM * K_DIM * 2;  // 64 MiB
  const size_t w_bytes  = (size_t)N_DIM * K_DIM * 2;  // 32 MiB

  if (ws_size >= xb_bytes + w_bytes) {
    unsigned short* xb = (unsigned short*)d_ws;
    unsigned short* W  = (unsigned short*)((char*)d_ws + xb_bytes);

    const int cvt_blocks = (M_DIM * K_DIM) / 8 / 256;   // 16384
    sl_prep<<<N_DIM + cvt_blocks, 256, 0, stream>>>(
        (const float4*)x, (u16x8*)xb, vals, rows, cols, W, nnz);
    sl_gemm_bias<<<dim3(M_DIM / BM, N_DIM / BN), 256, 0, stream>>>(xb, W, bias, out);
  } else {
    sl_naive<<<N_DIM, 256, 0, stream>>>(x, vals, rows, cols, bias, out, nnz);
  }
}

// Round 3
// 477.806 us; speedup vs baseline: 1.1749x; 1.1749x over previous
//
#include <hip/hip_runtime.h>
#include <hip/hip_bf16.h>

#define M_DIM 8192
#define N_DIM 4096
#define K_DIM 4096
#define BM 128
#define BN 128
#define BK 64

typedef __bf16 bf16x8 __attribute__((ext_vector_type(8)));
typedef float  f32x4  __attribute__((ext_vector_type(4)));
typedef unsigned short u16x8 __attribute__((ext_vector_type(8)));

// async global->LDS, 16B per lane, dest = wave-uniform base + lane*16
#define ASYNC16(g, l)                                                          \
  __builtin_amdgcn_global_load_lds(                                            \
      (__attribute__((address_space(1))) void*)(g),                            \
      (__attribute__((address_space(3))) void*)(l), 16, 0, 0)

static __device__ __forceinline__ unsigned short f2bf(float f) {
  unsigned int u = __float_as_uint(f);
  u += 0x7fffu + ((u >> 16) & 1u);   // round-to-nearest-even
  return (unsigned short)(u >> 16);
}

// ---- row boundaries of the (row-sorted) COO --------------------------------
__global__ void sl_bounds(const int* __restrict__ rows, int* __restrict__ row_start,
                          int* __restrict__ row_end, int nnz) {
  int k = blockIdx.x * 256 + threadIdx.x;
  if (k >= nnz) return;
  int r = rows[k];
  if (k == 0 || rows[k - 1] != r) row_start[r] = k;
  if (k == nnz - 1 || rows[k + 1] != r) row_end[r] = k + 1;
}

// ---- fused prep: blocks [0,N) build W rows CSR-style; rest convert x --------
__global__ __launch_bounds__(256) void sl_prep(
    const float4* __restrict__ x4, u16x8* __restrict__ xb,
    const float* __restrict__ vals, const int* __restrict__ cols,
    const int* __restrict__ row_start, const int* __restrict__ row_end,
    unsigned short* __restrict__ W) {
  const int b = blockIdx.x;
  if (b < N_DIM) {
    __shared__ __align__(16) unsigned short rowbuf[K_DIM];  // 8 KB
    u16x8* rb8 = (u16x8*)rowbuf;
    u16x8 z = {};
    rb8[threadIdx.x] = z;
    rb8[256 + threadIdx.x] = z;
    __syncthreads();
    const int s = row_start[b];
    const int e = row_end[b];
    for (int k = s + threadIdx.x; k < e; k += 256)
      rowbuf[cols[k]] = f2bf(vals[k]);
    __syncthreads();
    u16x8* dst = (u16x8*)(W + (size_t)b * K_DIM);
    dst[threadIdx.x] = rb8[threadIdx.x];
    dst[256 + threadIdx.x] = rb8[256 + threadIdx.x];
  } else {
    // x fp32 -> bf16, 8 elements/thread
    const int i = (b - N_DIM) * 256 + threadIdx.x;
    float4 a = x4[2 * i];
    float4 c = x4[2 * i + 1];
    u16x8 o;
    o[0] = f2bf(a.x); o[1] = f2bf(a.y); o[2] = f2bf(a.z); o[3] = f2bf(a.w);
    o[4] = f2bf(c.x); o[5] = f2bf(c.y); o[6] = f2bf(c.z); o[7] = f2bf(c.w);
    xb[i] = o;
  }
}

// ---- old prep with binary search (fallback when ws lacks the 32KB idx) ------
__global__ __launch_bounds__(256) void sl_prep_bs(
    const float4* __restrict__ x4, u16x8* __restrict__ xb,
    const float* __restrict__ vals, const int* __restrict__ rows,
    const int* __restrict__ cols, unsigned short* __restrict__ W, int nnz) {
  const int b = blockIdx.x;
  if (b < N_DIM) {
    __shared__ __align__(16) unsigned short rowbuf[K_DIM];
    u16x8* rb8 = (u16x8*)rowbuf;
    u16x8 z = {};
    rb8[threadIdx.x] = z;
    rb8[256 + threadIdx.x] = z;
    __syncthreads();
    int l = 0, h = nnz;
    while (l < h) { int m = (l + h) >> 1; if (rows[m] < b) l = m + 1; else h = m; }
    const int s = l;
    h = nnz;
    while (l < h) { int m = (l + h) >> 1; if (rows[m] <= b) l = m + 1; else h = m; }
    const int e = l;
    for (int k = s + threadIdx.x; k < e; k += 256)
      rowbuf[cols[k]] = f2bf(vals[k]);
    __syncthreads();
    u16x8* dst = (u16x8*)(W + (size_t)b * K_DIM);
    dst[threadIdx.x] = rb8[threadIdx.x];
    dst[256 + threadIdx.x] = rb8[256 + threadIdx.x];
  } else {
    const int i = (b - N_DIM) * 256 + threadIdx.x;
    float4 a = x4[2 * i];
    float4 c = x4[2 * i + 1];
    u16x8 o;
    o[0] = f2bf(a.x); o[1] = f2bf(a.y); o[2] = f2bf(a.z); o[3] = f2bf(a.w);
    o[4] = f2bf(c.x); o[5] = f2bf(c.y); o[6] = f2bf(c.z); o[7] = f2bf(c.w);
    xb[i] = o;
  }
}

// ---- bf16 MFMA GEMM: C[m][n] = sum_k A[m,k]*B[n,k] + bias[n] ----------------
// block 256 = 4 waves (2x2), wave computes 64x64. BK=64: per tile-row 8 16B
// chunks; physical chunk p = c ^ (row&7) (XOR swizzle -> conflict-free b128
// reads; staging honors the HW-fixed LDS dest by swizzling the GLOBAL column).
// Pipeline: [sync: tile ready] -> ds_read all frags -> [sync: reads done] ->
// issue next tile's global_load_lds (same buffer, now safe) -> 32 MFMAs
// overlap the in-flight loads.
__global__ __launch_bounds__(256, 3) void sl_gemm_bias(
    const unsigned short* __restrict__ A,   // x bf16 [M,K]
    const unsigned short* __restrict__ B,   // W bf16 [N,K]
    const float* __restrict__ bias,
    float* __restrict__ C) {
  __shared__ __align__(16) unsigned short As[BM * BK]; // 16 KB
  __shared__ __align__(16) unsigned short Bs[BN * BK]; // 16 KB

  const int tid  = threadIdx.x;
  const int wave = tid >> 6;
  const int lane = tid & 63;
  const int m0 = blockIdx.x * BM;
  const int n0 = blockIdx.y * BN;

  // --- staging: round r covers rows r*32 + (tid>>3); within-row phys chunk
  //     tid&7 holds logical chunk (tid&7)^((tid>>3)&7)  (row&7 == (tid>>3)&7)
  const int srow = tid >> 3;                            // 0..31
  const int scol = ((tid & 7) ^ ((tid >> 3) & 7)) * 8;  // swizzled bf16 col in BK
  const unsigned short* gA = A + (size_t)(m0 + srow) * K_DIM + scol;
  const unsigned short* gB = B + (size_t)(n0 + srow) * K_DIM + scol;
  // LDS wave-uniform bases: phys chunk index = round*256 + tid ; lane adds *16B
  unsigned short* lA = As + (size_t)(wave * 64) * 8;
  unsigned short* lB = Bs + (size_t)(wave * 64) * 8;
  const size_t GROW = (size_t)32 * K_DIM;   // 32 rows ahead in global
  const size_t LROW = (size_t)256 * 8;      // 256 chunks ahead in LDS (elems)

  // --- fragment addressing
  const int wm   = (wave >> 1) * 64;
  const int wn   = (wave & 1) * 64;
  const int fm   = lane & 15;
  const int quad = lane >> 4;
  const int sw   = fm & 7;                 // row-dependent swizzle bits

  f32x4 acc[4][4] = {};

  // prologue: stage tile 0
#pragma unroll
  for (int r = 0; r < 4; ++r) {
    ASYNC16(gA + r * GROW, lA + r * LROW);
    ASYNC16(gB + r * GROW, lB + r * LROW);
  }
  gA += BK; gB += BK;

  for (int k0 = 0; k0 < K_DIM; k0 += BK) {
    __syncthreads();   // drains vmcnt -> LDS tiles complete

    bf16x8 af[4][2], bfr[4][2];
#pragma unroll
    for (int t = 0; t < 4; ++t) {
#pragma unroll
      for (int h = 0; h < 2; ++h) {
        const int pA = ((h * 4 + quad) ^ sw) * 8;   // phys chunk * 8 elems
        af[t][h]  = *(const bf16x8*)(As + (size_t)(wm + t * 16 + fm) * BK + pA);
        bfr[t][h] = *(const bf16x8*)(Bs + (size_t)(wn + t * 16 + fm) * BK + pA);
      }
    }
    __syncthreads();   // all waves done reading -> buffer reusable

    if (k0 + BK < K_DIM) {
#pragma unroll
      for (int r = 0; r < 4; ++r) {
        ASYNC16(gA + r * GROW, lA + r * LROW);
        ASYNC16(gB + r * GROW, lB + r * LROW);
      }
      gA += BK; gB += BK;
    }

#pragma unroll
    for (int h = 0; h < 2; ++h)
#pragma unroll
      for (int tm = 0; tm < 4; ++tm)
#pragma unroll
        for (int tn = 0; tn < 4; ++tn)
          acc[tm][tn] = __builtin_amdgcn_mfma_f32_16x16x32_bf16(
              af[tm][h], bfr[tn][h], acc[tm][tn], 0, 0, 0);
  }

  // --- epilogue: D row = A-index (quad*4+reg), col = B-index (lane&15)
  float bv[4];
#pragma unroll
  for (int tn = 0; tn < 4; ++tn) bv[tn] = bias[n0 + wn + tn * 16 + fm];

#pragma unroll
  for (int tm = 0; tm < 4; ++tm) {
    const int mbase = m0 + wm + tm * 16 + quad * 4;
#pragma unroll
    for (int tn = 0; tn < 4; ++tn) {
      const int n = n0 + wn + tn * 16 + fm;
      float* p = C + (size_t)mbase * N_DIM + n;
#pragma unroll
      for (int r = 0; r < 4; ++r)
        __builtin_nontemporal_store(acc[tm][tn][r] + bv[tn], p + (size_t)r * N_DIM);
    }
  }
}

// ---- fallback (only if workspace too small): naive fp32 SpMM ----------------
__global__ void sl_naive(const float* __restrict__ x, const float* __restrict__ vals,
                         const int* __restrict__ rows, const int* __restrict__ cols,
                         const float* __restrict__ bias, float* __restrict__ out,
                         int nnz) {
  const int o = blockIdx.x;
  int l = 0, h = nnz;
  while (l < h) { int m = (l + h) >> 1; if (rows[m] < o) l = m + 1; else h = m; }
  const int s = l;
  h = nnz;
  while (l < h) { int m = (l + h) >> 1; if (rows[m] <= o) l = m + 1; else h = m; }
  const int e = l;
  const float bv = bias[o];
  for (int b = threadIdx.x; b < M_DIM; b += blockDim.x) {
    float acc = bv;
    const float* xb = x + (size_t)b * K_DIM;
    for (int k = s; k < e; ++k) acc += vals[k] * xb[cols[k]];
    out[(size_t)b * N_DIM + o] = acc;
  }
}

extern "C" void kernel_launch(void* const* d_in, const int* in_sizes, int n_in,
                              void* d_out, int out_size, void* d_ws, size_t ws_size,
                              hipStream_t stream) {
  const float* x    = (const float*)d_in[0];
  const float* vals = (const float*)d_in[1];
  const int*   rows = (const int*)d_in[2];
  const int*   cols = (const int*)d_in[3];
  const float* bias = (const float*)d_in[4];
  float* out = (float*)d_out;
  const int nnz = in_sizes[1];

  const size_t xb_bytes  = (size_t)M_DIM * K_DIM * 2;  // 64 MiB
  const size_t w_bytes   = (size_t)N_DIM * K_DIM * 2;  // 32 MiB
  const size_t idx_bytes = (size_t)2 * N_DIM * 4;      // 32 KiB

  const int cvt_blocks = (M_DIM * K_DIM) / 8 / 256;    // 16384

  if (ws_size >= xb_bytes + w_bytes + idx_bytes) {
    unsigned short* xb = (unsigned short*)d_ws;
    unsigned short* W  = (unsigned short*)((char*)d_ws + xb_bytes);
    int* row_start = (int*)((char*)d_ws + xb_bytes + w_bytes);
    int* row_end   = row_start + N_DIM;

    hipMemsetAsync(row_start, 0, idx_bytes, stream);
    sl_bounds<<<(nnz + 255) / 256, 256, 0, stream>>>(rows, row_start, row_end, nnz);
    sl_prep<<<N_DIM + cvt_blocks, 256, 0, stream>>>(
        (const float4*)x, (u16x8*)xb, vals, cols, row_start, row_end, W);
    sl_gemm_bias<<<dim3(M_DIM / BM, N_DIM / BN), 256, 0, stream>>>(xb, W, bias, out);
  } else if (ws_size >= xb_bytes + w_bytes) {
    unsigned short* xb = (unsigned short*)d_ws;
    unsigned short* W  = (unsigned short*)((char*)d_ws + xb_bytes);
    sl_prep_bs<<<N_DIM + cvt_blocks, 256, 0, stream>>>(
        (const float4*)x, (u16x8*)xb, vals, rows, cols, W, nnz);
    sl_gemm_bias<<<dim3(M_DIM / BM, N_DIM / BN), 256, 0, stream>>>(xb, W, bias, out);
  } else {
    sl_naive<<<N_DIM, 256, 0, stream>>>(x, vals, rows, cols, bias, out, nnz);
  }
}